// Round 2
// baseline (1299.938 us; speedup 1.0000x reference)
//
#include <hip/hip_runtime.h>

#define N_PTS   200000
#define CIN     64
#define COUT    16
#define KK      27
#define SXD     998
#define SYD     998
#define SZD     38
#define STRX    (SYD*SZD)        /* 37924 */
#define SENTV   (SXD*SYD*SZD)    /* 37848152 */
#define NKTOT   (N_PTS*KK)       /* 5400000 */
#define NWORDS  ((SENTV+31)/32)  /* 1182755 */
#define NCHUNK  ((NWORDS+255)/256) /* 4621 */
#define NB      16000            /* (x>>3)*128+(y>>3), x,y<1000 */

typedef float f32x4 __attribute__((ext_vector_type(4)));

// ---------------- K1: mark occupied voxels (+optional bucket histogram) ------------
// The 3 z-offsets of one (ox,oy) are consecutive bits -> one atomicOr of up to 3 bits.
template<int S>
__global__ void mark_kernel(const int* __restrict__ coords, unsigned* __restrict__ bm,
                            unsigned* __restrict__ mu, unsigned* __restrict__ hist) {
    int n = blockIdx.x * blockDim.x + threadIdx.x;
    if (n >= N_PTS) return;
    int4 c = ((const int4*)coords)[n];
    int x = c.y, y = c.z, z = c.w;
    if (hist) {
        unsigned key = ((unsigned)x >> 3) * 128u + ((unsigned)y >> 3);
        atomicAdd(&hist[key], 1u);
    }
    int zlo = z - 2; if (zlo < 0) zlo = 0;
    int zhi = z;     if (zhi > SZD - 1) zhi = SZD - 1;
    unsigned nb = (unsigned)(zhi - zlo + 1);      // 1..3
    unsigned mseed = (1u << nb) - 1u;
    #pragma unroll
    for (int dx = 0; dx < 3; dx++) {
        int ox = x - dx;
        if (ox < 0 || ox >= SXD) continue;
        #pragma unroll
        for (int dy = 0; dy < 3; dy++) {
            int oy = y - dy;
            if (oy < 0 || oy >= SYD) continue;
            int lin = ox*STRX + oy*SZD + zlo;
            unsigned w = (unsigned)lin >> 5;
            unsigned b = (unsigned)lin & 31u;
            unsigned lowm = mseed << b;           // truncation = low-word part
            unsigned old = atomicOr(&bm[(size_t)w * S], lowm);
            unsigned col = old & lowm;
            if (col) atomicOr(&mu[(size_t)w * S], col);
            if (b + nb > 32u) {                   // b >= 30 here
                unsigned highm = mseed >> (32u - b);
                unsigned old2 = atomicOr(&bm[(size_t)(w+1) * S], highm);
                unsigned col2 = old2 & highm;
                if (col2) atomicOr(&mu[(size_t)(w+1) * S], col2);
            }
        }
    }
}

// ---------------- K2: per-256-word chunk popcount sums ----------------
template<int S>
__global__ void chunk_sums_kernel(const unsigned* __restrict__ bm, unsigned* __restrict__ csums) {
    int w = blockIdx.x * 256 + threadIdx.x;
    unsigned c = (w < NWORDS) ? (unsigned)__popc(bm[(size_t)w * S]) : 0u;
    __shared__ unsigned s[256];
    s[threadIdx.x] = c;
    __syncthreads();
    for (int off = 128; off > 0; off >>= 1) {
        if (threadIdx.x < off) s[threadIdx.x] += s[threadIdx.x + off];
        __syncthreads();
    }
    if (threadIdx.x == 0) csums[blockIdx.x] = s[0];
}

// ---------------- K3: single-block scans: chunk sums -> cprefix/U; hist -> bpos -----
__global__ void scan_all_kernel(const unsigned* __restrict__ csums,
                                unsigned* __restrict__ cprefix,
                                unsigned* __restrict__ Uptr,
                                const unsigned* __restrict__ hist,
                                unsigned* __restrict__ bpos,
                                int do_buckets) {
    __shared__ unsigned s[256];
    __shared__ unsigned run_s;
    if (threadIdx.x == 0) run_s = 0;
    __syncthreads();
    for (int base = 0; base < NCHUNK; base += 256) {
        int i = base + threadIdx.x;
        unsigned v = (i < NCHUNK) ? csums[i] : 0u;
        s[threadIdx.x] = v;
        __syncthreads();
        for (int off = 1; off < 256; off <<= 1) {
            unsigned t = (threadIdx.x >= off) ? s[threadIdx.x - off] : 0u;
            __syncthreads();
            s[threadIdx.x] += t;
            __syncthreads();
        }
        unsigned run = run_s;
        if (i < NCHUNK) cprefix[i] = run + s[threadIdx.x] - v;
        unsigned tile_total = s[255];
        __syncthreads();
        if (threadIdx.x == 255) run_s = run + tile_total;
        __syncthreads();
    }
    if (threadIdx.x == 0) Uptr[0] = run_s;
    if (!do_buckets) return;
    __syncthreads();
    if (threadIdx.x == 0) run_s = 0;
    __syncthreads();
    for (int base = 0; base < NB; base += 256) {
        int i = base + threadIdx.x;
        unsigned v = (i < NB) ? hist[i] : 0u;
        s[threadIdx.x] = v;
        __syncthreads();
        for (int off = 1; off < 256; off <<= 1) {
            unsigned t = (threadIdx.x >= off) ? s[threadIdx.x - off] : 0u;
            __syncthreads();
            s[threadIdx.x] += t;
            __syncthreads();
        }
        unsigned run = run_s;
        if (i < NB) bpos[i] = run + s[threadIdx.x] - v;
        unsigned tile_total = s[255];
        __syncthreads();
        if (threadIdx.x == 255) run_s = run + tile_total;
        __syncthreads();
    }
}

// ---------------- K4: per-word exclusive prefix into wp ----------------
template<int S>
__global__ void word_prefix_kernel(const unsigned* __restrict__ bm,
                                   const unsigned* __restrict__ cprefix,
                                   unsigned* __restrict__ wp) {
    int w = blockIdx.x * 256 + threadIdx.x;
    unsigned v = (w < NWORDS) ? (unsigned)__popc(bm[(size_t)w * S]) : 0u;
    __shared__ unsigned s[256];
    s[threadIdx.x] = v;
    __syncthreads();
    for (int off = 1; off < 256; off <<= 1) {
        unsigned t = (threadIdx.x >= off) ? s[threadIdx.x - off] : 0u;
        __syncthreads();
        s[threadIdx.x] += t;
        __syncthreads();
    }
    if (w < NWORDS) wp[(size_t)w * S] = cprefix[blockIdx.x] + s[threadIdx.x] - v;
}

// ---------------- K4b: counting-sort scatter; carry point id in .x ------------------
__global__ void pidx_kernel(const int* __restrict__ coords, unsigned* __restrict__ bpos,
                            int4* __restrict__ csorted) {
    int n = blockIdx.x * blockDim.x + threadIdx.x;
    if (n >= N_PTS) return;
    int4 c = ((const int4*)coords)[n];
    unsigned key = ((unsigned)c.y >> 3) * 128u + ((unsigned)c.z >> 3);
    unsigned pos = atomicAdd(&bpos[key], 1u);
    csorted[pos] = make_int4(n, c.y, c.z, c.w);
}

// ---------------- fallback-path fills (ws too small) ----------------
__global__ void fill_out_kernel(float* __restrict__ out, const float* __restrict__ bias,
                                const unsigned* __restrict__ Uptr) {
    unsigned U = Uptr[0];
    unsigned i = blockIdx.x * blockDim.x + threadIdx.x;  // quarter-row index
    if (i >= (unsigned)NKTOT * 4u) return;
    unsigned row = i >> 2;
    int q = i & 3;
    float4 v;
    if (row < U) v = ((const float4*)bias)[q];
    else         v = make_float4(0.f, 0.f, 0.f, 0.f);
    ((float4*)out)[i] = v;
}

__global__ void fill_uniq_kernel(float* __restrict__ uniq) {
    unsigned i = blockIdx.x * blockDim.x + threadIdx.x;
    if (i < (unsigned)NKTOT) uniq[i] = (float)SENTV;
}

// ---------------- K5 (fast path): zeros + SENT only for tail rows >= U -------------
__global__ void tail_kernel(float* __restrict__ out, float* __restrict__ uniq,
                            const unsigned* __restrict__ Uptr) {
    unsigned U = Uptr[0];
    unsigned i = blockIdx.x * blockDim.x + threadIdx.x;   // row index
    if (i >= (unsigned)NKTOT || i < U) return;
    f32x4 z4 = {0.f, 0.f, 0.f, 0.f};
    f32x4* dst = (f32x4*)(out + (size_t)i * COUT);
    #pragma unroll
    for (int q = 0; q < 4; q++) __builtin_nontemporal_store(z4, dst + q);
    __builtin_nontemporal_store((float)SENTV, uniq + i);
}

// ---------------- K6: uniq ids via LDS (coalesced); bias-init multi rows ------------
template<int S, bool DO_BIAS>
__global__ void write_uniq_kernel(const unsigned* __restrict__ bm,
                                  const unsigned* __restrict__ mu,
                                  const unsigned* __restrict__ wp,
                                  const unsigned* __restrict__ Uptr,
                                  float* __restrict__ uniq,
                                  float* __restrict__ out,
                                  const float* __restrict__ bias) {
    __shared__ float sbuf[8192];                 // max 256 words * 32 bits
    unsigned U = Uptr[0];
    int wfirst = blockIdx.x * 256;
    int wnext  = wfirst + 256;
    unsigned r0 = wp[(size_t)wfirst * S];        // wfirst < NWORDS by grid construction
    unsigned r1 = (wnext < NWORDS) ? wp[(size_t)wnext * S] : U;
    int w = wfirst + threadIdx.x;
    unsigned bits = 0, r = 0, mbits = 0;
    if (w < NWORDS) {
        bits = bm[(size_t)w * S];
        r    = wp[(size_t)w * S];
        if (DO_BIAS) mbits = mu[(size_t)w * S];
    }
    unsigned bb = bits, rr = r;
    while (bb) {
        int b = __ffs(bb) - 1;
        bb &= bb - 1;
        sbuf[rr - r0] = (float)((unsigned)w * 32u + b);
        rr++;
    }
    __syncthreads();
    unsigned span = r1 - r0;
    for (unsigned j = threadIdx.x; j < span; j += 256)
        __builtin_nontemporal_store(sbuf[j], uniq + r0 + j);
    if (DO_BIAS && bits && mbits) {
        f32x4 bv[4];
        #pragma unroll
        for (int q = 0; q < 4; q++) bv[q] = ((const f32x4*)bias)[q];
        bb = bits; rr = r;
        while (bb) {
            int b = __ffs(bb) - 1;
            bb &= bb - 1;
            if ((mbits >> b) & 1u) {
                f32x4* dst = (f32x4*)(out + (size_t)rr * COUT);
                #pragma unroll
                for (int q = 0; q < 4; q++) __builtin_nontemporal_store(bv[q], dst + q);
            }
            rr++;
        }
    }
}

// ---------------- K7: main scatter GEMV (spatially sorted; 1 meta line per tap) -----
template<int S, bool SORTED>
__launch_bounds__(64)
__global__ void scatter_mm_kernel(const float* __restrict__ feats,
                                  const int4* __restrict__ cpts,
                                  const float* __restrict__ W,
                                  const float* __restrict__ bias,
                                  const unsigned* __restrict__ bm,
                                  const unsigned* __restrict__ mu,
                                  const unsigned* __restrict__ wp,
                                  float* __restrict__ out) {
    int i = blockIdx.x * 64 + threadIdx.x;
    if (i >= N_PTS) return;
    int4 cc = cpts[i];
    int n = SORTED ? cc.x : i;
    int x = cc.y, y = cc.z, z = cc.w;

    // feature row in registers (16 float4 = 64 VGPRs); nt: streamed once
    f32x4 f[CIN/4];
    const f32x4* fin4 = (const f32x4*)(feats + (size_t)n * CIN);
    #pragma unroll
    for (int q = 0; q < CIN/4; q++) f[q] = __builtin_nontemporal_load(fin4 + q);

    f32x4 bv[4];
    #pragma unroll
    for (int q = 0; q < 4; q++) bv[q] = ((const f32x4*)bias)[q];

    #pragma unroll 1
    for (int m = 0; m < KK; m++) {
        int ox = x - (m/9), oy = y - ((m/3)%3), oz = z - (m%3);
        if (ox < 0 || ox >= SXD || oy < 0 || oy >= SYD || oz < 0 || oz >= SZD) continue;
        int lin = ox*STRX + oy*SZD + oz;
        unsigned word = (unsigned)lin >> 5, bit = (unsigned)lin & 31u;
        unsigned rank;
        bool is_multi;
        if constexpr (S == 4) {
            uint4 md = ((const uint4*)bm)[word];          // one 16B line per tap
            rank = md.z + (unsigned)__popc(md.x & ((1u << bit) - 1u));
            is_multi = (md.y >> bit) & 1u;
        } else {
            rank = wp[word] + (unsigned)__popc(bm[word] & ((1u << bit) - 1u));
            is_multi = (mu[word] >> bit) & 1u;
        }

        const float* wk = W + (size_t)m * CIN * COUT;  // m uniform -> scalar loads
        float acc[COUT];
        #pragma unroll
        for (int o = 0; o < COUT; o++) acc[o] = 0.f;
        #pragma unroll
        for (int c4 = 0; c4 < CIN/4; c4++) {
            f32x4 fv = f[c4];
            const float* wrow = wk + c4 * 4 * COUT;
            #pragma unroll
            for (int o = 0; o < COUT; o++) {
                acc[o] += fv.x * wrow[o] + fv.y * wrow[COUT + o]
                        + fv.z * wrow[2*COUT + o] + fv.w * wrow[3*COUT + o];
            }
        }

        float* dst = out + (size_t)rank * COUT;
        if (!is_multi) {
            #pragma unroll
            for (int q = 0; q < 4; q++) {
                f32x4 v;
                v.x = acc[q*4+0] + bv[q].x;
                v.y = acc[q*4+1] + bv[q].y;
                v.z = acc[q*4+2] + bv[q].z;
                v.w = acc[q*4+3] + bv[q].w;
                __builtin_nontemporal_store(v, ((f32x4*)dst) + q);
            }
        } else {
            #pragma unroll
            for (int o = 0; o < COUT; o++) atomicAdd(dst + o, acc[o]);
        }
    }
}

extern "C" void kernel_launch(void* const* d_in, const int* in_sizes, int n_in,
                              void* d_out, int out_size, void* d_ws, size_t ws_size,
                              hipStream_t stream) {
    const float* feats  = (const float*)d_in[0];
    const int*   coords = (const int*)d_in[1];
    const float* W      = (const float*)d_in[2];
    const float* bias   = (const float*)d_in[3];
    float* out  = (float*)d_out;
    float* uniq = out + (size_t)NKTOT * COUT;

    unsigned* ws = (unsigned*)d_ws;

    // ---- fast-path layout ----
    // meta uint4-interleaved: [4w]=bitmap, [4w+1]=multi, [4w+2]=wprefix, [4w+3]=pad
    size_t o_meta    = 0;
    size_t o_hist    = o_meta + 4 * (size_t)NWORDS;
    size_t o_bpos    = o_hist + NB;
    size_t o_csums   = o_bpos + NB;
    size_t o_cprefix = o_csums + NCHUNK;
    size_t o_Uptr    = o_cprefix + NCHUNK;
    size_t o_csort   = (o_Uptr + 1 + 3) & ~(size_t)3;   // int4-aligned
    size_t fast_words = o_csort + 4 * (size_t)N_PTS;

    if (ws_size >= fast_words * sizeof(unsigned)) {
        unsigned* meta    = ws + o_meta;
        unsigned* hist    = ws + o_hist;
        unsigned* bpos    = ws + o_bpos;
        unsigned* csums   = ws + o_csums;
        unsigned* cprefix = ws + o_cprefix;
        unsigned* Uptr    = ws + o_Uptr;
        int4*     csorted = (int4*)(ws + o_csort);

        hipMemsetAsync(meta, 0, (4 * (size_t)NWORDS + NB) * sizeof(unsigned), stream);
        mark_kernel<4><<<(N_PTS + 255) / 256, 256, 0, stream>>>(coords, meta, meta + 1, hist);
        chunk_sums_kernel<4><<<NCHUNK, 256, 0, stream>>>(meta, csums);
        scan_all_kernel<<<1, 256, 0, stream>>>(csums, cprefix, Uptr, hist, bpos, 1);
        pidx_kernel<<<(N_PTS + 255) / 256, 256, 0, stream>>>(coords, bpos, csorted);
        word_prefix_kernel<4><<<NCHUNK, 256, 0, stream>>>(meta, cprefix, meta + 2);
        write_uniq_kernel<4, true><<<NCHUNK, 256, 0, stream>>>(
            meta, meta + 1, meta + 2, Uptr, uniq, out, bias);
        tail_kernel<<<(NKTOT + 255) / 256, 256, 0, stream>>>(out, uniq, Uptr);
        scatter_mm_kernel<4, true><<<(N_PTS + 63) / 64, 64, 0, stream>>>(
            feats, csorted, W, bias, meta, meta + 1, meta + 2, out);
    } else {
        // fallback: multi aliased to bitmap -> every row treated as multi (pure atomics)
        unsigned* bitmap  = ws;
        unsigned* wprefix = ws + NWORDS;
        unsigned* csums   = ws + 2 * (size_t)NWORDS;
        unsigned* cprefix = csums + NCHUNK;
        unsigned* Uptr    = cprefix + NCHUNK;

        hipMemsetAsync(bitmap, 0, (size_t)NWORDS * sizeof(unsigned), stream);
        mark_kernel<1><<<(N_PTS + 255) / 256, 256, 0, stream>>>(coords, bitmap, bitmap, nullptr);
        chunk_sums_kernel<1><<<NCHUNK, 256, 0, stream>>>(bitmap, csums);
        scan_all_kernel<<<1, 256, 0, stream>>>(csums, cprefix, Uptr, nullptr, nullptr, 0);
        word_prefix_kernel<1><<<NCHUNK, 256, 0, stream>>>(bitmap, cprefix, wprefix);
        fill_out_kernel<<<(NKTOT * 4 + 255) / 256, 256, 0, stream>>>(out, bias, Uptr);
        fill_uniq_kernel<<<(NKTOT + 255) / 256, 256, 0, stream>>>(uniq);
        write_uniq_kernel<1, false><<<NCHUNK, 256, 0, stream>>>(
            bitmap, bitmap, wprefix, Uptr, uniq, out, bias);
        scatter_mm_kernel<1, false><<<(N_PTS + 63) / 64, 64, 0, stream>>>(
            feats, (const int4*)coords, W, bias, bitmap, bitmap, wprefix, out);
    }
}

// Round 3
// 1251.366 us; speedup vs baseline: 1.0388x; 1.0388x over previous
//
#include <hip/hip_runtime.h>

#define N_PTS   200000
#define CIN     64
#define COUT    16
#define KK      27
#define SXD     998
#define SYD     998
#define SZD     38
#define STRX    (SYD*SZD)        /* 37924 */
#define SENTV   (SXD*SYD*SZD)    /* 37848152 */
#define NKTOT   (N_PTS*KK)       /* 5400000 */
#define NWORDS  ((SENTV+31)/32)  /* 1182755 */
#define NCHUNK  ((NWORDS+255)/256) /* 4621 */
#define NB      16000            /* (x>>3)*128+(y>>3), x,y<1000 */

typedef float f32x4 __attribute__((ext_vector_type(4)));

// ---------------- K1: mark occupied voxels (+optional bucket histogram) ------------
// The 3 z-offsets of one (ox,oy) are consecutive bits -> one atomicOr of up to 3 bits.
template<int S>
__global__ void mark_kernel(const int* __restrict__ coords, unsigned* __restrict__ bm,
                            unsigned* __restrict__ mu, unsigned* __restrict__ hist) {
    int n = blockIdx.x * blockDim.x + threadIdx.x;
    if (n >= N_PTS) return;
    int4 c = ((const int4*)coords)[n];
    int x = c.y, y = c.z, z = c.w;
    if (hist) {
        unsigned key = ((unsigned)x >> 3) * 128u + ((unsigned)y >> 3);
        atomicAdd(&hist[key], 1u);
    }
    int zlo = z - 2; if (zlo < 0) zlo = 0;
    int zhi = z;     if (zhi > SZD - 1) zhi = SZD - 1;
    unsigned nb = (unsigned)(zhi - zlo + 1);      // 1..3
    unsigned mseed = (1u << nb) - 1u;
    #pragma unroll
    for (int dx = 0; dx < 3; dx++) {
        int ox = x - dx;
        if (ox < 0 || ox >= SXD) continue;
        #pragma unroll
        for (int dy = 0; dy < 3; dy++) {
            int oy = y - dy;
            if (oy < 0 || oy >= SYD) continue;
            int lin = ox*STRX + oy*SZD + zlo;
            unsigned w = (unsigned)lin >> 5;
            unsigned b = (unsigned)lin & 31u;
            unsigned lowm = mseed << b;           // truncation = low-word part
            unsigned old = atomicOr(&bm[(size_t)w * S], lowm);
            unsigned col = old & lowm;
            if (col) atomicOr(&mu[(size_t)w * S], col);
            if (b + nb > 32u) {                   // b >= 30 here
                unsigned highm = mseed >> (32u - b);
                unsigned old2 = atomicOr(&bm[(size_t)(w+1) * S], highm);
                unsigned col2 = old2 & highm;
                if (col2) atomicOr(&mu[(size_t)(w+1) * S], col2);
            }
        }
    }
}

// ---------------- K2: per-256-word chunk popcount sums ----------------
template<int S>
__global__ void chunk_sums_kernel(const unsigned* __restrict__ bm, unsigned* __restrict__ csums) {
    int w = blockIdx.x * 256 + threadIdx.x;
    unsigned c = (w < NWORDS) ? (unsigned)__popc(bm[(size_t)w * S]) : 0u;
    __shared__ unsigned s[256];
    s[threadIdx.x] = c;
    __syncthreads();
    for (int off = 128; off > 0; off >>= 1) {
        if (threadIdx.x < off) s[threadIdx.x] += s[threadIdx.x + off];
        __syncthreads();
    }
    if (threadIdx.x == 0) csums[blockIdx.x] = s[0];
}

// ---------------- K3: single-block scans: chunk sums -> cprefix/U; hist -> bpos -----
__global__ void scan_all_kernel(const unsigned* __restrict__ csums,
                                unsigned* __restrict__ cprefix,
                                unsigned* __restrict__ Uptr,
                                const unsigned* __restrict__ hist,
                                unsigned* __restrict__ bpos,
                                int do_buckets) {
    __shared__ unsigned s[256];
    __shared__ unsigned run_s;
    if (threadIdx.x == 0) run_s = 0;
    __syncthreads();
    for (int base = 0; base < NCHUNK; base += 256) {
        int i = base + threadIdx.x;
        unsigned v = (i < NCHUNK) ? csums[i] : 0u;
        s[threadIdx.x] = v;
        __syncthreads();
        for (int off = 1; off < 256; off <<= 1) {
            unsigned t = (threadIdx.x >= off) ? s[threadIdx.x - off] : 0u;
            __syncthreads();
            s[threadIdx.x] += t;
            __syncthreads();
        }
        unsigned run = run_s;
        if (i < NCHUNK) cprefix[i] = run + s[threadIdx.x] - v;
        unsigned tile_total = s[255];
        __syncthreads();
        if (threadIdx.x == 255) run_s = run + tile_total;
        __syncthreads();
    }
    if (threadIdx.x == 0) Uptr[0] = run_s;
    if (!do_buckets) return;
    __syncthreads();
    if (threadIdx.x == 0) run_s = 0;
    __syncthreads();
    for (int base = 0; base < NB; base += 256) {
        int i = base + threadIdx.x;
        unsigned v = (i < NB) ? hist[i] : 0u;
        s[threadIdx.x] = v;
        __syncthreads();
        for (int off = 1; off < 256; off <<= 1) {
            unsigned t = (threadIdx.x >= off) ? s[threadIdx.x - off] : 0u;
            __syncthreads();
            s[threadIdx.x] += t;
            __syncthreads();
        }
        unsigned run = run_s;
        if (i < NB) bpos[i] = run + s[threadIdx.x] - v;
        unsigned tile_total = s[255];
        __syncthreads();
        if (threadIdx.x == 255) run_s = run + tile_total;
        __syncthreads();
    }
}

// ---------------- K4: per-word exclusive prefix into wp ----------------
template<int S>
__global__ void word_prefix_kernel(const unsigned* __restrict__ bm,
                                   const unsigned* __restrict__ cprefix,
                                   unsigned* __restrict__ wp) {
    int w = blockIdx.x * 256 + threadIdx.x;
    unsigned v = (w < NWORDS) ? (unsigned)__popc(bm[(size_t)w * S]) : 0u;
    __shared__ unsigned s[256];
    s[threadIdx.x] = v;
    __syncthreads();
    for (int off = 1; off < 256; off <<= 1) {
        unsigned t = (threadIdx.x >= off) ? s[threadIdx.x - off] : 0u;
        __syncthreads();
        s[threadIdx.x] += t;
        __syncthreads();
    }
    if (w < NWORDS) wp[(size_t)w * S] = cprefix[blockIdx.x] + s[threadIdx.x] - v;
}

// ---------------- K4b: counting-sort scatter; carry point id in .x ------------------
__global__ void pidx_kernel(const int* __restrict__ coords, unsigned* __restrict__ bpos,
                            int4* __restrict__ csorted) {
    int n = blockIdx.x * blockDim.x + threadIdx.x;
    if (n >= N_PTS) return;
    int4 c = ((const int4*)coords)[n];
    unsigned key = ((unsigned)c.y >> 3) * 128u + ((unsigned)c.z >> 3);
    unsigned pos = atomicAdd(&bpos[key], 1u);
    csorted[pos] = make_int4(n, c.y, c.z, c.w);
}

// ---------------- fallback-path fills (ws too small) ----------------
__global__ void fill_out_kernel(float* __restrict__ out, const float* __restrict__ bias,
                                const unsigned* __restrict__ Uptr) {
    unsigned U = Uptr[0];
    unsigned i = blockIdx.x * blockDim.x + threadIdx.x;  // quarter-row index
    if (i >= (unsigned)NKTOT * 4u) return;
    unsigned row = i >> 2;
    int q = i & 3;
    float4 v;
    if (row < U) v = ((const float4*)bias)[q];
    else         v = make_float4(0.f, 0.f, 0.f, 0.f);
    ((float4*)out)[i] = v;
}

__global__ void fill_uniq_kernel(float* __restrict__ uniq) {
    unsigned i = blockIdx.x * blockDim.x + threadIdx.x;
    if (i < (unsigned)NKTOT) uniq[i] = (float)SENTV;
}

// ---------------- K5 (fast path): zeros + SENT only for tail rows >= U -------------
__global__ void tail_kernel(float* __restrict__ out, float* __restrict__ uniq,
                            const unsigned* __restrict__ Uptr) {
    unsigned U = Uptr[0];
    unsigned i = blockIdx.x * blockDim.x + threadIdx.x;   // row index
    if (i >= (unsigned)NKTOT || i < U) return;
    f32x4 z4 = {0.f, 0.f, 0.f, 0.f};
    f32x4* dst = (f32x4*)(out + (size_t)i * COUT);
    #pragma unroll
    for (int q = 0; q < 4; q++) __builtin_nontemporal_store(z4, dst + q);
    __builtin_nontemporal_store((float)SENTV, uniq + i);
}

// ---------------- K6: uniq ids via LDS (coalesced); bias-init multi rows ------------
template<int S, bool DO_BIAS>
__global__ void write_uniq_kernel(const unsigned* __restrict__ bm,
                                  const unsigned* __restrict__ mu,
                                  const unsigned* __restrict__ wp,
                                  const unsigned* __restrict__ Uptr,
                                  float* __restrict__ uniq,
                                  float* __restrict__ out,
                                  const float* __restrict__ bias) {
    __shared__ float sbuf[8192];                 // max 256 words * 32 bits
    unsigned U = Uptr[0];
    int wfirst = blockIdx.x * 256;
    int wnext  = wfirst + 256;
    unsigned r0 = wp[(size_t)wfirst * S];        // wfirst < NWORDS by grid construction
    unsigned r1 = (wnext < NWORDS) ? wp[(size_t)wnext * S] : U;
    int w = wfirst + threadIdx.x;
    unsigned bits = 0, r = 0, mbits = 0;
    if (w < NWORDS) {
        bits = bm[(size_t)w * S];
        r    = wp[(size_t)w * S];
        if (DO_BIAS) mbits = mu[(size_t)w * S];
    }
    unsigned bb = bits, rr = r;
    while (bb) {
        int b = __ffs(bb) - 1;
        bb &= bb - 1;
        sbuf[rr - r0] = (float)((unsigned)w * 32u + b);
        rr++;
    }
    __syncthreads();
    unsigned span = r1 - r0;
    for (unsigned j = threadIdx.x; j < span; j += 256)
        __builtin_nontemporal_store(sbuf[j], uniq + r0 + j);
    if (DO_BIAS && bits && mbits) {
        f32x4 bv[4];
        #pragma unroll
        for (int q = 0; q < 4; q++) bv[q] = ((const f32x4*)bias)[q];
        bb = bits; rr = r;
        while (bb) {
            int b = __ffs(bb) - 1;
            bb &= bb - 1;
            if ((mbits >> b) & 1u) {
                f32x4* dst = (f32x4*)(out + (size_t)rr * COUT);
                #pragma unroll
                for (int q = 0; q < 4; q++) __builtin_nontemporal_store(bv[q], dst + q);
            }
            rr++;
        }
    }
}

// ---------------- K7: main scatter GEMV --------------------------------------------
// dx-split: blockIdx.y = dx (3 planes), 9 taps/thread -> 3x waves for latency hiding.
// Sole-row stores are CACHED (L2 write-combining; sorted ranks give line locality).
template<int S, bool SORTED>
__launch_bounds__(256)
__global__ void scatter_mm_kernel(const float* __restrict__ feats,
                                  const int4* __restrict__ cpts,
                                  const float* __restrict__ W,
                                  const float* __restrict__ bias,
                                  const unsigned* __restrict__ bm,
                                  const unsigned* __restrict__ mu,
                                  const unsigned* __restrict__ wp,
                                  float* __restrict__ out) {
    int i = blockIdx.x * 256 + threadIdx.x;
    if (i >= N_PTS) return;
    int dx = blockIdx.y;
    int4 cc = cpts[i];
    int n = SORTED ? cc.x : i;
    int x = cc.y, y = cc.z, z = cc.w;
    int ox = x - dx;
    if (ox < 0 || ox >= SXD) return;

    // feature row in registers (16 float4 = 64 VGPRs); cached (shared across 3 dx planes)
    f32x4 f[CIN/4];
    const f32x4* fin4 = (const f32x4*)(feats + (size_t)n * CIN);
    #pragma unroll
    for (int q = 0; q < CIN/4; q++) f[q] = fin4[q];

    f32x4 bv[4];
    #pragma unroll
    for (int q = 0; q < 4; q++) bv[q] = ((const f32x4*)bias)[q];

    #pragma unroll 1
    for (int dy = 0; dy < 3; dy++) {
        int oy = y - dy;
        if (oy < 0 || oy >= SYD) continue;
        int colbase = ox*STRX + oy*SZD;
        #pragma unroll 1
        for (int dz = 0; dz < 3; dz++) {
            int oz = z - dz;
            if (oz < 0 || oz >= SZD) continue;
            int lin = colbase + oz;
            unsigned word = (unsigned)lin >> 5, bit = (unsigned)lin & 31u;
            unsigned rank;
            bool is_multi;
            if constexpr (S == 4) {
                uint4 md = ((const uint4*)bm)[word];          // one 16B line per tap
                rank = md.z + (unsigned)__popc(md.x & ((1u << bit) - 1u));
                is_multi = (md.y >> bit) & 1u;
            } else {
                rank = wp[word] + (unsigned)__popc(bm[word] & ((1u << bit) - 1u));
                is_multi = (mu[word] >> bit) & 1u;
            }

            int m = dx*9 + dy*3 + dz;
            const float* wk = W + (size_t)m * CIN * COUT;  // m uniform -> scalar loads
            float acc[COUT];
            #pragma unroll
            for (int o = 0; o < COUT; o++) acc[o] = 0.f;
            #pragma unroll
            for (int c4 = 0; c4 < CIN/4; c4++) {
                f32x4 fv = f[c4];
                const float* wrow = wk + c4 * 4 * COUT;
                #pragma unroll
                for (int o = 0; o < COUT; o++) {
                    acc[o] += fv.x * wrow[o] + fv.y * wrow[COUT + o]
                            + fv.z * wrow[2*COUT + o] + fv.w * wrow[3*COUT + o];
                }
            }

            float* dst = out + (size_t)rank * COUT;
            if (!is_multi) {
                // sole contributor: cached stores; sorted ranks -> L2 line co-write
                #pragma unroll
                for (int q = 0; q < 4; q++) {
                    f32x4 v;
                    v.x = acc[q*4+0] + bv[q].x;
                    v.y = acc[q*4+1] + bv[q].y;
                    v.z = acc[q*4+2] + bv[q].z;
                    v.w = acc[q*4+3] + bv[q].w;
                    ((f32x4*)dst)[q] = v;
                }
            } else {
                #pragma unroll
                for (int o = 0; o < COUT; o++) atomicAdd(dst + o, acc[o]);
            }
        }
    }
}

extern "C" void kernel_launch(void* const* d_in, const int* in_sizes, int n_in,
                              void* d_out, int out_size, void* d_ws, size_t ws_size,
                              hipStream_t stream) {
    const float* feats  = (const float*)d_in[0];
    const int*   coords = (const int*)d_in[1];
    const float* W      = (const float*)d_in[2];
    const float* bias   = (const float*)d_in[3];
    float* out  = (float*)d_out;
    float* uniq = out + (size_t)NKTOT * COUT;

    unsigned* ws = (unsigned*)d_ws;

    // ---- fast-path layout ----
    // meta uint4-interleaved: [4w]=bitmap, [4w+1]=multi, [4w+2]=wprefix, [4w+3]=pad
    size_t o_meta    = 0;
    size_t o_hist    = o_meta + 4 * (size_t)NWORDS;
    size_t o_bpos    = o_hist + NB;
    size_t o_csums   = o_bpos + NB;
    size_t o_cprefix = o_csums + NCHUNK;
    size_t o_Uptr    = o_cprefix + NCHUNK;
    size_t o_csort   = (o_Uptr + 1 + 3) & ~(size_t)3;   // int4-aligned
    size_t fast_words = o_csort + 4 * (size_t)N_PTS;

    if (ws_size >= fast_words * sizeof(unsigned)) {
        unsigned* meta    = ws + o_meta;
        unsigned* hist    = ws + o_hist;
        unsigned* bpos    = ws + o_bpos;
        unsigned* csums   = ws + o_csums;
        unsigned* cprefix = ws + o_cprefix;
        unsigned* Uptr    = ws + o_Uptr;
        int4*     csorted = (int4*)(ws + o_csort);

        hipMemsetAsync(meta, 0, (4 * (size_t)NWORDS + NB) * sizeof(unsigned), stream);
        mark_kernel<4><<<(N_PTS + 255) / 256, 256, 0, stream>>>(coords, meta, meta + 1, hist);
        chunk_sums_kernel<4><<<NCHUNK, 256, 0, stream>>>(meta, csums);
        scan_all_kernel<<<1, 256, 0, stream>>>(csums, cprefix, Uptr, hist, bpos, 1);
        pidx_kernel<<<(N_PTS + 255) / 256, 256, 0, stream>>>(coords, bpos, csorted);
        word_prefix_kernel<4><<<NCHUNK, 256, 0, stream>>>(meta, cprefix, meta + 2);
        write_uniq_kernel<4, true><<<NCHUNK, 256, 0, stream>>>(
            meta, meta + 1, meta + 2, Uptr, uniq, out, bias);
        tail_kernel<<<(NKTOT + 255) / 256, 256, 0, stream>>>(out, uniq, Uptr);
        scatter_mm_kernel<4, true><<<dim3((N_PTS + 255) / 256, 3), 256, 0, stream>>>(
            feats, csorted, W, bias, meta, meta + 1, meta + 2, out);
    } else {
        // fallback: multi aliased to bitmap -> every row treated as multi (pure atomics)
        unsigned* bitmap  = ws;
        unsigned* wprefix = ws + NWORDS;
        unsigned* csums   = ws + 2 * (size_t)NWORDS;
        unsigned* cprefix = csums + NCHUNK;
        unsigned* Uptr    = cprefix + NCHUNK;

        hipMemsetAsync(bitmap, 0, (size_t)NWORDS * sizeof(unsigned), stream);
        mark_kernel<1><<<(N_PTS + 255) / 256, 256, 0, stream>>>(coords, bitmap, bitmap, nullptr);
        chunk_sums_kernel<1><<<NCHUNK, 256, 0, stream>>>(bitmap, csums);
        scan_all_kernel<<<1, 256, 0, stream>>>(csums, cprefix, Uptr, nullptr, nullptr, 0);
        word_prefix_kernel<1><<<NCHUNK, 256, 0, stream>>>(bitmap, cprefix, wprefix);
        fill_out_kernel<<<(NKTOT * 4 + 255) / 256, 256, 0, stream>>>(out, bias, Uptr);
        fill_uniq_kernel<<<(NKTOT + 255) / 256, 256, 0, stream>>>(uniq);
        write_uniq_kernel<1, false><<<NCHUNK, 256, 0, stream>>>(
            bitmap, bitmap, wprefix, Uptr, uniq, out, bias);
        scatter_mm_kernel<1, false><<<dim3((N_PTS + 255) / 256, 3), 256, 0, stream>>>(
            feats, (const int4*)coords, W, bias, bitmap, bitmap, wprefix, out);
    }
}